// Round 1
// baseline (670.240 us; speedup 1.0000x reference)
//
#include <hip/hip_runtime.h>
#include <hip/hip_bf16.h>

// Problem constants
#define BATCH 4
#define SEQ   2048
#define HID   1024
#define HEADS 16
#define HDIM  64
#define MROWS (BATCH * SEQ)   // 8192

typedef short v8s __attribute__((ext_vector_type(8)));
typedef float v4f __attribute__((ext_vector_type(4)));

#define MFMA16(a, b, c) __builtin_amdgcn_mfma_f32_16x16x32_bf16((a), (b), (c), 0, 0, 0)

__device__ inline unsigned short f2b(float f) {
    unsigned int u = __float_as_uint(f);
    unsigned int r = (u + 0x7FFFu + ((u >> 16) & 1u)) >> 16;
    return (unsigned short)r;
}
__device__ inline float b2f(unsigned short u) {
    return __uint_as_float(((unsigned int)u) << 16);
}

// ---------------- prep: x f32 -> bf16 ----------------
__global__ __launch_bounds__(256) void cvt_x(const float* __restrict__ x,
                                             ushort* __restrict__ xb) {
    int i = blockIdx.x * 256 + threadIdx.x;     // one thread = 8 elems
    const float4* xp = (const float4*)x;
    float4 a = xp[2 * i];
    float4 b = xp[2 * i + 1];
    ushort4 o1, o2;
    o1.x = f2b(a.x); o1.y = f2b(a.y); o1.z = f2b(a.z); o1.w = f2b(a.w);
    o2.x = f2b(b.x); o2.y = f2b(b.y); o2.z = f2b(b.z); o2.w = f2b(b.w);
    ((ushort4*)xb)[2 * i]     = o1;
    ((ushort4*)xb)[2 * i + 1] = o2;
}

// ---------------- prep: W [K][N] f32 -> Wt [N][K] bf16 ----------------
__global__ __launch_bounds__(256) void transw(const float* __restrict__ W,
                                              ushort* __restrict__ Wt) {
    __shared__ float t[32][33];
    int bx = blockIdx.x * 32, by = blockIdx.y * 32;
    int tx = threadIdx.x, ty = threadIdx.y;     // (32, 8)
#pragma unroll
    for (int i = 0; i < 4; i++)
        t[ty + i * 8][tx] = W[(size_t)(by + ty + i * 8) * HID + bx + tx];
    __syncthreads();
#pragma unroll
    for (int i = 0; i < 4; i++)
        Wt[(size_t)(bx + ty + i * 8) * HID + by + tx] = f2b(t[tx][ty + i * 8]);
}

// ---------------- prep: bias bf16 = mask ? -|a|*t : -1e9 ----------------
__global__ __launch_bounds__(256) void mkbias(const float* __restrict__ tiv,
                                              const int* __restrict__ msk,
                                              const float* __restrict__ alphap,
                                              ushort* __restrict__ bias) {
    int i = blockIdx.x * 256 + threadIdx.x;     // one thread = 4 elems
    float a = -fabsf(alphap[0]);
    float4 tv = ((const float4*)tiv)[i];
    int4  mv = ((const int4*)msk)[i];
    ushort4 o;
    o.x = f2b(mv.x == 0 ? -1e9f : a * tv.x);
    o.y = f2b(mv.y == 0 ? -1e9f : a * tv.y);
    o.z = f2b(mv.z == 0 ? -1e9f : a * tv.z);
    o.w = f2b(mv.w == 0 ? -1e9f : a * tv.w);
    ((ushort4*)bias)[i] = o;
}

// ---------------- QKV projection GEMM ----------------
// C[m][n] = sum_k xb[m][k] * Wt[n][k]  (+ proj bias[n])
// mode z: 0 -> Q [b][h][s][d], 1 -> K [b][h][s][d], 2 -> V^T [b][h][d][s]
#define LDT 72   // padded LDS row stride (bf16 elems)

__global__ __launch_bounds__(256) void gemm_qkv(
    const ushort* __restrict__ xb, const ushort* __restrict__ wt,
    const float* __restrict__ bq, const float* __restrict__ bk,
    const float* __restrict__ bv,
    ushort* __restrict__ Qb, ushort* __restrict__ Kb, ushort* __restrict__ Vtb) {
    const int mode = blockIdx.z;
    const ushort* w = wt + (size_t)mode * HID * HID;
    __shared__ ushort As[128 * LDT];
    __shared__ ushort Bs[128 * LDT];
    const int tid = threadIdx.x;
    const int wv = tid >> 6, lane = tid & 63;
    const int quad = lane >> 4, l15 = lane & 15;
    const int wr = wv >> 1, wc = wv & 1;
    const int m0 = blockIdx.y * 128;
    const int n0 = blockIdx.x * 128;

    v4f acc[4][4];
#pragma unroll
    for (int i = 0; i < 4; i++)
#pragma unroll
        for (int j = 0; j < 4; j++) acc[i][j] = (v4f){0.f, 0.f, 0.f, 0.f};

    const int sr = tid >> 3;            // 0..31
    const int sc = (tid & 7) * 8;       // 0..56
    const ushort* Ag = xb + (size_t)m0 * HID;
    const ushort* Bg = w + (size_t)n0 * HID;

    for (int k0 = 0; k0 < HID; k0 += 64) {
        __syncthreads();
#pragma unroll
        for (int i = 0; i < 4; i++) {
            int r = sr + i * 32;
            *(uint4*)&As[r * LDT + sc] = *(const uint4*)&Ag[(size_t)r * HID + k0 + sc];
            *(uint4*)&Bs[r * LDT + sc] = *(const uint4*)&Bg[(size_t)r * HID + k0 + sc];
        }
        __syncthreads();
#pragma unroll
        for (int kc = 0; kc < 2; kc++) {
            v8s af[4], bf[4];
#pragma unroll
            for (int t = 0; t < 4; t++) {
                af[t] = *(const v8s*)&As[(wr * 64 + t * 16 + l15) * LDT + kc * 32 + quad * 8];
                bf[t] = *(const v8s*)&Bs[(wc * 64 + t * 16 + l15) * LDT + kc * 32 + quad * 8];
            }
#pragma unroll
            for (int tm = 0; tm < 4; tm++)
#pragma unroll
                for (int tn = 0; tn < 4; tn++)
                    acc[tm][tn] = MFMA16(af[tm], bf[tn], acc[tm][tn]);
        }
    }

    const float* pb = (mode == 0) ? bq : (mode == 1 ? bk : bv);
#pragma unroll
    for (int tm = 0; tm < 4; tm++) {
#pragma unroll
        for (int tn = 0; tn < 4; tn++) {
            int n = n0 + wc * 64 + tn * 16 + l15;
            float bval = pb[n];
            int h = n >> 6, d = n & 63;
#pragma unroll
            for (int r = 0; r < 4; r++) {
                int m = m0 + wr * 64 + tm * 16 + quad * 4 + r;
                int b = m >> 11, s = m & 2047;
                unsigned short hv = f2b(acc[tm][tn][r] + bval);
                if (mode == 2) {
                    Vtb[(((size_t)(b * HEADS + h) * HDIM + d) * SEQ) + s] = hv;
                } else {
                    ushort* dst = (mode == 0) ? Qb : Kb;
                    dst[((size_t)(b * HEADS + h) * SEQ + s) * HDIM + d] = hv;
                }
            }
        }
    }
}

// ---------------- flash attention ----------------
// grid (16 q-tiles, 64 b*h); block 256 (4 waves); wave owns 32 q-rows.
__global__ __launch_bounds__(256) void attn(
    const ushort* __restrict__ Qb, const ushort* __restrict__ Kb,
    const ushort* __restrict__ Vtb, const ushort* __restrict__ biasb,
    float* __restrict__ out) {
    const int bh = blockIdx.y;
    const int b = bh >> 4, h = bh & 15;
    const int qt = blockIdx.x;
    const int tid = threadIdx.x;
    const int wv = tid >> 6, lane = tid & 63;
    const int quad = lane >> 4, l15 = lane & 15;

    __shared__ ushort Ks[64 * LDT];       // [key][d], padded
    __shared__ ushort Vs[64 * LDT];       // [d][key], padded
    __shared__ ushort Ps[4][32 * LDT];    // per-wave P, padded
    __shared__ ushort Bi[4][32 * 64];     // per-wave bias tile (scalar reads)

    const int q0 = qt * 128 + wv * 32;

    const ushort* Qp = Qb + (size_t)(b * HEADS + h) * SEQ * HDIM;
    const ushort* Kp = Kb + (size_t)(b * HEADS + h) * SEQ * HDIM;
    const ushort* Vp = Vtb + (size_t)(b * HEADS + h) * HDIM * SEQ;
    const ushort* Bp = biasb + ((size_t)b * SEQ + q0) * SEQ;

    v8s qf[2][2];
#pragma unroll
    for (int tm = 0; tm < 2; tm++)
#pragma unroll
        for (int kc = 0; kc < 2; kc++)
            qf[tm][kc] = *(const v8s*)&Qp[(size_t)(q0 + tm * 16 + l15) * HDIM + kc * 32 + quad * 8];

    v4f oacc[2][4];
#pragma unroll
    for (int i = 0; i < 2; i++)
#pragma unroll
        for (int j = 0; j < 4; j++) oacc[i][j] = (v4f){0.f, 0.f, 0.f, 0.f};
    float mrun[2][4], lrun[2][4];
#pragma unroll
    for (int i = 0; i < 2; i++)
#pragma unroll
        for (int j = 0; j < 4; j++) { mrun[i][j] = -INFINITY; lrun[i][j] = 0.f; }

    for (int kt = 0; kt < SEQ / 64; kt++) {
        const int key0 = kt * 64;
        __syncthreads();
        // stage K tile [64][64] and V^T tile [64][64]
#pragma unroll
        for (int i = 0; i < 2; i++) {
            int idx = tid + 256 * i;
            int rr = idx >> 3, cc = (idx & 7) * 8;
            *(uint4*)&Ks[rr * LDT + cc] = *(const uint4*)&Kp[(size_t)(key0 + rr) * HDIM + cc];
            *(uint4*)&Vs[rr * LDT + cc] = *(const uint4*)&Vp[(size_t)rr * SEQ + key0 + cc];
        }
        // stage per-wave bias tile [32][64]
#pragma unroll
        for (int i = 0; i < 4; i++) {
            int idx = lane + 64 * i;
            int rr = idx >> 3, cc = (idx & 7) * 8;
            *(uint4*)&Bi[wv][rr * 64 + cc] = *(const uint4*)&Bp[(size_t)rr * SEQ + key0 + cc];
        }
        __syncthreads();

        // S = Q K^T
        v4f sacc[2][4];
#pragma unroll
        for (int i = 0; i < 2; i++)
#pragma unroll
            for (int j = 0; j < 4; j++) sacc[i][j] = (v4f){0.f, 0.f, 0.f, 0.f};
#pragma unroll
        for (int kc = 0; kc < 2; kc++) {
            v8s kf[4];
#pragma unroll
            for (int nt = 0; nt < 4; nt++)
                kf[nt] = *(const v8s*)&Ks[(nt * 16 + l15) * LDT + kc * 32 + quad * 8];
#pragma unroll
            for (int tm = 0; tm < 2; tm++)
#pragma unroll
                for (int nt = 0; nt < 4; nt++)
                    sacc[tm][nt] = MFMA16(qf[tm][kc], kf[nt], sacc[tm][nt]);
        }

        // online softmax (rows live in C/D layout: q = quad*4+r per tm-tile)
#pragma unroll
        for (int tm = 0; tm < 2; tm++) {
#pragma unroll
            for (int r = 0; r < 4; r++) {
                int qrow = tm * 16 + quad * 4 + r;
                float sv[4];
#pragma unroll
                for (int nt = 0; nt < 4; nt++)
                    sv[nt] = sacc[tm][nt][r] * 0.125f + b2f(Bi[wv][qrow * 64 + nt * 16 + l15]);
                float mx = fmaxf(fmaxf(sv[0], sv[1]), fmaxf(sv[2], sv[3]));
#pragma unroll
                for (int off = 1; off < 16; off <<= 1)
                    mx = fmaxf(mx, __shfl_xor(mx, off, 64));
                float mnew = fmaxf(mrun[tm][r], mx);
                float al = __expf(mrun[tm][r] - mnew);
                float rs = 0.f;
#pragma unroll
                for (int nt = 0; nt < 4; nt++) {
                    float p = __expf(sv[nt] - mnew);
                    rs += p;
                    Ps[wv][qrow * LDT + nt * 16 + l15] = f2b(p);
                }
#pragma unroll
                for (int off = 1; off < 16; off <<= 1)
                    rs += __shfl_xor(rs, off, 64);
                lrun[tm][r] = lrun[tm][r] * al + rs;
                mrun[tm][r] = mnew;
#pragma unroll
                for (int nt = 0; nt < 4; nt++)
                    oacc[tm][nt][r] *= al;
            }
        }

        // O += P V   (P via LDS layout round-trip; V^T rows are d)
#pragma unroll
        for (int kc = 0; kc < 2; kc++) {
            v8s pf[2], vf[4];
#pragma unroll
            for (int tm = 0; tm < 2; tm++)
                pf[tm] = *(const v8s*)&Ps[wv][(tm * 16 + l15) * LDT + kc * 32 + quad * 8];
#pragma unroll
            for (int nt = 0; nt < 4; nt++)
                vf[nt] = *(const v8s*)&Vs[(nt * 16 + l15) * LDT + kc * 32 + quad * 8];
#pragma unroll
            for (int tm = 0; tm < 2; tm++)
#pragma unroll
                for (int nt = 0; nt < 4; nt++)
                    oacc[tm][nt] = MFMA16(pf[tm], vf[nt], oacc[tm][nt]);
        }
    }

    // epilogue: out[b][q][h*64+d] = oacc / l
#pragma unroll
    for (int tm = 0; tm < 2; tm++)
#pragma unroll
        for (int nt = 0; nt < 4; nt++)
#pragma unroll
            for (int r = 0; r < 4; r++) {
                int q = q0 + tm * 16 + quad * 4 + r;
                int d = nt * 16 + l15;
                out[((size_t)b * SEQ + q) * HID + h * HDIM + d] =
                    oacc[tm][nt][r] / lrun[tm][r];
            }
}

// ---------------- launch ----------------
extern "C" void kernel_launch(void* const* d_in, const int* in_sizes, int n_in,
                              void* d_out, int out_size, void* d_ws, size_t ws_size,
                              hipStream_t stream) {
    const float* x    = (const float*)d_in[0];
    const float* tiv  = (const float*)d_in[1];
    const int*   msk  = (const int*)d_in[2];
    const float* Wq   = (const float*)d_in[3];
    const float* bq   = (const float*)d_in[4];
    const float* Wk   = (const float*)d_in[5];
    const float* bk   = (const float*)d_in[6];
    const float* Wv   = (const float*)d_in[7];
    const float* bv   = (const float*)d_in[8];
    const float* alp  = (const float*)d_in[9];

    char* ws = (char*)d_ws;
    const size_t XB_OFF = 0;                                  // 16,777,216 B
    const size_t WT_OFF = XB_OFF + (size_t)MROWS * HID * 2;   // + 6,291,456 B
    const size_t Q_OFF  = WT_OFF + (size_t)3 * HID * HID * 2; // + 16,777,216 B
    const size_t K_OFF  = Q_OFF + (size_t)MROWS * HID * 2;
    const size_t V_OFF  = K_OFF + (size_t)MROWS * HID * 2;
    const size_t B_OFF  = V_OFF + (size_t)MROWS * HID * 2;    // bias: 33,554,432 B

    ushort* xb   = (ushort*)(ws + XB_OFF);
    ushort* wt   = (ushort*)(ws + WT_OFF);
    ushort* Qb   = (ushort*)(ws + Q_OFF);
    ushort* Kb   = (ushort*)(ws + K_OFF);
    ushort* Vtb  = (ushort*)(ws + V_OFF);
    ushort* bias = (ushort*)(ws + B_OFF);

    cvt_x<<<MROWS * HID / (256 * 8), 256, 0, stream>>>(x, xb);
    dim3 tb(32, 8);
    transw<<<dim3(32, 32), tb, 0, stream>>>(Wq, wt);
    transw<<<dim3(32, 32), tb, 0, stream>>>(Wk, wt + HID * HID);
    transw<<<dim3(32, 32), tb, 0, stream>>>(Wv, wt + 2 * HID * HID);
    mkbias<<<(size_t)BATCH * SEQ * SEQ / (256 * 4), 256, 0, stream>>>(tiv, msk, alp, bias);
    gemm_qkv<<<dim3(HID / 128, MROWS / 128, 3), 256, 0, stream>>>(
        xb, wt, bq, bk, bv, Qb, Kb, Vtb);
    attn<<<dim3(SEQ / 128, BATCH * HEADS), 256, 0, stream>>>(Qb, Kb, Vtb, bias,
                                                             (float*)d_out);
}

// Round 2
// 436.096 us; speedup vs baseline: 1.5369x; 1.5369x over previous
//
#include <hip/hip_runtime.h>
#include <hip/hip_bf16.h>
#include <hip/hip_fp16.h>

// Problem constants
#define BATCH 4
#define SEQ   2048
#define HID   1024
#define HEADS 16
#define HDIM  64
#define MROWS (BATCH * SEQ)   // 8192
#define LOG2E 1.4426950408889634f
#define SCL   (LOG2E / 8.0f)  // log2e / sqrt(HDIM)

typedef _Float16 v8h __attribute__((ext_vector_type(8)));
typedef _Float16 v4h __attribute__((ext_vector_type(4)));
typedef _Float16 v2h __attribute__((ext_vector_type(2)));
typedef float    v4f __attribute__((ext_vector_type(4)));
typedef int      v4i __attribute__((ext_vector_type(4)));

#define MFMA16(a, b, c) __builtin_amdgcn_mfma_f32_16x16x32_f16((a), (b), (c), 0, 0, 0)

__device__ inline int pk2(float a, float b) {
    return __builtin_bit_cast(int, __builtin_amdgcn_cvt_pkrtz(a, b));
}

// ---------------- prep: x f32 -> f16 ----------------
__global__ __launch_bounds__(256) void cvt_x(const float* __restrict__ x,
                                             _Float16* __restrict__ xb) {
    int i = blockIdx.x * 256 + threadIdx.x;     // one thread = 8 elems
    const float4* xp = (const float4*)x;
    float4 a = xp[2 * i];
    float4 b = xp[2 * i + 1];
    v4i o;
    o[0] = pk2(a.x, a.y); o[1] = pk2(a.z, a.w);
    o[2] = pk2(b.x, b.y); o[3] = pk2(b.z, b.w);
    ((v4i*)xb)[i] = o;
}

// ---------------- prep: W [K][N] f32 -> Wt [N][K] f16 ----------------
__global__ __launch_bounds__(256) void transw(const float* __restrict__ W,
                                              _Float16* __restrict__ Wt) {
    __shared__ float t[32][33];
    int bx = blockIdx.x * 32, by = blockIdx.y * 32;
    int tx = threadIdx.x, ty = threadIdx.y;     // (32, 8)
#pragma unroll
    for (int i = 0; i < 4; i++)
        t[ty + i * 8][tx] = W[(size_t)(by + ty + i * 8) * HID + bx + tx];
    __syncthreads();
#pragma unroll
    for (int i = 0; i < 4; i++)
        Wt[(size_t)(bx + ty + i * 8) * HID + by + tx] = (_Float16)t[tx][ty + i * 8];
}

// ---------------- prep: permuted bias (MFMA S^T fragment order, f16) ----
// biasT[b][K16][Q16][lane][r] = mask ? -|a|*log2e*t : -57344
// where k = K16*16 + (lane>>4)*4 + r, q = Q16*16 + (lane&15)
__global__ __launch_bounds__(256) void mkbias(const float* __restrict__ tiv,
                                              const int* __restrict__ msk,
                                              const float* __restrict__ alphap,
                                              _Float16* __restrict__ biasT) {
    __shared__ _Float16 L[16 * 264];
    const int b = blockIdx.z, Q16 = blockIdx.y, kc0 = blockIdx.x * 256;
    const int tid = threadIdx.x;
    const float ca = -fabsf(alphap[0]) * LOG2E;
    const int prow = tid >> 6;          // 0..3
    const int pcol = (tid & 63) * 4;    // 0..252
#pragma unroll
    for (int pi = 0; pi < 4; pi++) {
        int r = pi * 4 + prow;
        size_t g = ((size_t)b * SEQ + Q16 * 16 + r) * SEQ + kc0 + pcol;
        float4 tv = *(const float4*)(tiv + g);
        int4   mv = *(const int4*)(msk + g);
        float f0 = mv.x ? ca * tv.x : -57344.0f;
        float f1 = mv.y ? ca * tv.y : -57344.0f;
        float f2 = mv.z ? ca * tv.z : -57344.0f;
        float f3 = mv.w ? ca * tv.w : -57344.0f;
        int2 o; o.x = pk2(f0, f1); o.y = pk2(f2, f3);
        *(int2*)&L[r * 264 + pcol] = o;
    }
    __syncthreads();
    const int lane = tid & 63, tq = tid >> 6;
#pragma unroll
    for (int it = 0; it < 4; it++) {
        int K16i = it * 4 + tq;
        int kl = K16i * 16 + (lane >> 4) * 4;
        int qr = lane & 15;
        int2 v = *(const int2*)&L[qr * 264 + kl];
        size_t o = ((((size_t)b * 128 + (kc0 >> 4) + K16i) * 128 + Q16) * 64 + lane) * 4;
        *(int2*)&biasT[o] = v;
    }
}

// ---------------- QKV projection GEMM (f16) ----------------
#define LDT 72   // padded LDS row stride (f16 elems)

__global__ __launch_bounds__(256) void gemm_qkv(
    const _Float16* __restrict__ xb, const _Float16* __restrict__ wt,
    const float* __restrict__ bq, const float* __restrict__ bk,
    const float* __restrict__ bv,
    _Float16* __restrict__ Qb, _Float16* __restrict__ Kb, _Float16* __restrict__ Vtb) {
    const int mode = blockIdx.z;
    const _Float16* w = wt + (size_t)mode * HID * HID;
    __shared__ _Float16 As[128 * LDT];
    __shared__ _Float16 Bs[128 * LDT];
    const int tid = threadIdx.x;
    const int wv = tid >> 6, lane = tid & 63;
    const int quad = lane >> 4, l15 = lane & 15;
    const int wr = wv >> 1, wc = wv & 1;
    const int m0 = blockIdx.y * 128;
    const int n0 = blockIdx.x * 128;

    v4f acc[4][4];
#pragma unroll
    for (int i = 0; i < 4; i++)
#pragma unroll
        for (int j = 0; j < 4; j++) acc[i][j] = (v4f){0.f, 0.f, 0.f, 0.f};

    const int sr = tid >> 3;            // 0..31
    const int sc = (tid & 7) * 8;       // 0..56
    const _Float16* Ag = xb + (size_t)m0 * HID;
    const _Float16* Bg = w + (size_t)n0 * HID;

    for (int k0 = 0; k0 < HID; k0 += 64) {
        __syncthreads();
#pragma unroll
        for (int i = 0; i < 4; i++) {
            int r = sr + i * 32;
            *(uint4*)&As[r * LDT + sc] = *(const uint4*)&Ag[(size_t)r * HID + k0 + sc];
            *(uint4*)&Bs[r * LDT + sc] = *(const uint4*)&Bg[(size_t)r * HID + k0 + sc];
        }
        __syncthreads();
#pragma unroll
        for (int kc = 0; kc < 2; kc++) {
            v8h af[4], bf[4];
#pragma unroll
            for (int t = 0; t < 4; t++) {
                af[t] = *(const v8h*)&As[(wr * 64 + t * 16 + l15) * LDT + kc * 32 + quad * 8];
                bf[t] = *(const v8h*)&Bs[(wc * 64 + t * 16 + l15) * LDT + kc * 32 + quad * 8];
            }
#pragma unroll
            for (int tm = 0; tm < 4; tm++)
#pragma unroll
                for (int tn = 0; tn < 4; tn++)
                    acc[tm][tn] = MFMA16(af[tm], bf[tn], acc[tm][tn]);
        }
    }

    const float* pb = (mode == 0) ? bq : (mode == 1 ? bk : bv);
#pragma unroll
    for (int tm = 0; tm < 4; tm++) {
#pragma unroll
        for (int tn = 0; tn < 4; tn++) {
            int n = n0 + wc * 64 + tn * 16 + l15;
            float bval = pb[n];
            int h = n >> 6, d = n & 63;
#pragma unroll
            for (int r = 0; r < 4; r++) {
                int m = m0 + wr * 64 + tm * 16 + quad * 4 + r;
                int b = m >> 11, s = m & 2047;
                _Float16 hv = (_Float16)(acc[tm][tn][r] + bval);
                if (mode == 2) {
                    Vtb[(((size_t)(b * HEADS + h) * HDIM + d) * SEQ) + s] = hv;
                } else {
                    _Float16* dst = (mode == 0) ? Qb : Kb;
                    dst[((size_t)(b * HEADS + h) * SEQ + s) * HDIM + d] = hv;
                }
            }
        }
    }
}

// ---------------- flash attention (S^T form, no online max) ----------------
// grid (16 q-tiles, 64 b*h); block 256 (4 waves); wave owns 32 q-rows.
__global__ __launch_bounds__(256, 4) void attn(
    const _Float16* __restrict__ Qb, const _Float16* __restrict__ Kb,
    const _Float16* __restrict__ Vtb, const _Float16* __restrict__ biasT,
    float* __restrict__ out) {
    const int bh = blockIdx.y;
    const int b = bh >> 4, h = bh & 15;
    const int qt = blockIdx.x;
    const int tid = threadIdx.x;
    const int wv = tid >> 6, lane = tid & 63;
    const int quad = lane >> 4, l15 = lane & 15;

    __shared__ _Float16 Ks[64 * LDT];     // [key][d], padded
    __shared__ _Float16 Vs[64 * LDT];     // [d][key], padded

    const int q0 = qt * 128 + wv * 32;
    const int Q16a = q0 >> 4;             // + tm

    const _Float16* Qp = Qb + (size_t)(b * HEADS + h) * SEQ * HDIM;
    const _Float16* Kp = Kb + (size_t)(b * HEADS + h) * SEQ * HDIM;
    const _Float16* Vp = Vtb + (size_t)(b * HEADS + h) * HDIM * SEQ;
    const _Float16* Bbase = biasT + (size_t)b * 128 * 128 * 64 * 4;

    // Q fragments (B-operand: lane l15 = qrow, k = d)
    v8h qf[2][2];
#pragma unroll
    for (int tm = 0; tm < 2; tm++)
#pragma unroll
        for (int kc = 0; kc < 2; kc++)
            qf[tm][kc] = *(const v8h*)&Qp[(size_t)(q0 + tm * 16 + l15) * HDIM + kc * 32 + quad * 8];

    v4f oacc[2][4];
#pragma unroll
    for (int i = 0; i < 2; i++)
#pragma unroll
        for (int j = 0; j < 4; j++) oacc[i][j] = (v4f){0.f, 0.f, 0.f, 0.f};
    float lsum[2] = {0.f, 0.f};

    // bpermute source byte-addresses (fixed per lane)
    const int addrA = ((quad & 1) * 32 + l15) * 4;
    const int addrB = addrA + 64;
    const bool hiq = (quad >= 2);

    for (int kt = 0; kt < SEQ / 64; kt++) {
        const int key0 = kt * 64;
        // bias fragments straight from global (permuted layout, L2-hot)
        int2 bld[4][2];
#pragma unroll
        for (int nt = 0; nt < 4; nt++)
#pragma unroll
            for (int tm = 0; tm < 2; tm++)
                bld[nt][tm] = *(const int2*)&Bbase[((((size_t)(key0 >> 4) + nt) * 128 + Q16a + tm) * 64 + lane) * 4];

        __syncthreads();
#pragma unroll
        for (int i = 0; i < 2; i++) {
            int idx = tid + 256 * i;
            int rr = idx >> 3, cc = (idx & 7) * 8;
            *(uint4*)&Ks[rr * LDT + cc] = *(const uint4*)&Kp[(size_t)(key0 + rr) * HDIM + cc];
            *(uint4*)&Vs[rr * LDT + cc] = *(const uint4*)&Vp[(size_t)rr * SEQ + key0 + cc];
        }
        __syncthreads();

        // S^T = K Q^T : C/D row = key (quad*4+r), col = qrow (l15)
        v4f sacc[4][2];
#pragma unroll
        for (int i = 0; i < 4; i++)
#pragma unroll
            for (int j = 0; j < 2; j++) sacc[i][j] = (v4f){0.f, 0.f, 0.f, 0.f};
#pragma unroll
        for (int kc = 0; kc < 2; kc++) {
            v8h kfr[4];
#pragma unroll
            for (int nt = 0; nt < 4; nt++)
                kfr[nt] = *(const v8h*)&Ks[(nt * 16 + l15) * LDT + kc * 32 + quad * 8];
#pragma unroll
            for (int nt = 0; nt < 4; nt++)
#pragma unroll
                for (int tm = 0; tm < 2; tm++)
                    sacc[nt][tm] = MFMA16(kfr[nt], qf[tm][kc], sacc[nt][tm]);
        }

        // p = exp2(s*scl + bias2); accumulate per-lane partial row sums
        int pk[4][2][2];
#pragma unroll
        for (int nt = 0; nt < 4; nt++)
#pragma unroll
            for (int tm = 0; tm < 2; tm++) {
                v4h bv = __builtin_bit_cast(v4h, bld[nt][tm]);
                float p0 = __builtin_amdgcn_exp2f(sacc[nt][tm][0] * SCL + (float)bv[0]);
                float p1 = __builtin_amdgcn_exp2f(sacc[nt][tm][1] * SCL + (float)bv[1]);
                float p2 = __builtin_amdgcn_exp2f(sacc[nt][tm][2] * SCL + (float)bv[2]);
                float p3 = __builtin_amdgcn_exp2f(sacc[nt][tm][3] * SCL + (float)bv[3]);
                lsum[tm] += (p0 + p1) + (p2 + p3);
                pk[nt][tm][0] = pk2(p0, p1);
                pk[nt][tm][1] = pk2(p2, p3);
            }

        // exchange: build A-fragment of P (m = qrow, k = key) via ds_bpermute
        v8h pf[2][2];
#pragma unroll
        for (int kc = 0; kc < 2; kc++)
#pragma unroll
            for (int tm = 0; tm < 2; tm++) {
                int d0l = __builtin_amdgcn_ds_bpermute(addrA, pk[kc * 2][tm][0]);
                int d0h = __builtin_amdgcn_ds_bpermute(addrA, pk[kc * 2 + 1][tm][0]);
                int d1l = __builtin_amdgcn_ds_bpermute(addrA, pk[kc * 2][tm][1]);
                int d1h = __builtin_amdgcn_ds_bpermute(addrA, pk[kc * 2 + 1][tm][1]);
                int d2l = __builtin_amdgcn_ds_bpermute(addrB, pk[kc * 2][tm][0]);
                int d2h = __builtin_amdgcn_ds_bpermute(addrB, pk[kc * 2 + 1][tm][0]);
                int d3l = __builtin_amdgcn_ds_bpermute(addrB, pk[kc * 2][tm][1]);
                int d3h = __builtin_amdgcn_ds_bpermute(addrB, pk[kc * 2 + 1][tm][1]);
                v4i dw;
                dw[0] = hiq ? d0h : d0l;
                dw[1] = hiq ? d1h : d1l;
                dw[2] = hiq ? d2h : d2l;
                dw[3] = hiq ? d3h : d3l;
                pf[kc][tm] = __builtin_bit_cast(v8h, dw);
            }

        // O += P V  (B-frag of V from V^T staging: lane l15 = d, k = key)
#pragma unroll
        for (int kc = 0; kc < 2; kc++) {
            v8h vfr[4];
#pragma unroll
            for (int nt = 0; nt < 4; nt++)
                vfr[nt] = *(const v8h*)&Vs[(nt * 16 + l15) * LDT + kc * 32 + quad * 8];
#pragma unroll
            for (int tm = 0; tm < 2; tm++)
#pragma unroll
                for (int nt = 0; nt < 4; nt++)
                    oacc[tm][nt] = MFMA16(pf[kc][tm], vfr[nt], oacc[tm][nt]);
        }
    }

    // epilogue: reduce row sums across quads, fetch per-C/D-row inverse, store
#pragma unroll
    for (int tm = 0; tm < 2; tm++) {
        float lt = lsum[tm];
        lt += __shfl_xor(lt, 16);
        lt += __shfl_xor(lt, 32);
        float inv[4];
#pragma unroll
        for (int r = 0; r < 4; r++)
            inv[r] = 1.0f / __shfl(lt, quad * 4 + r);
#pragma unroll
        for (int nt = 0; nt < 4; nt++)
#pragma unroll
            for (int r = 0; r < 4; r++) {
                int q = q0 + tm * 16 + quad * 4 + r;
                int d = nt * 16 + l15;
                out[((size_t)b * SEQ + q) * HID + h * HDIM + d] = oacc[tm][nt][r] * inv[r];
            }
    }
}

// ---------------- launch ----------------
extern "C" void kernel_launch(void* const* d_in, const int* in_sizes, int n_in,
                              void* d_out, int out_size, void* d_ws, size_t ws_size,
                              hipStream_t stream) {
    const float* x    = (const float*)d_in[0];
    const float* tiv  = (const float*)d_in[1];
    const int*   msk  = (const int*)d_in[2];
    const float* Wq   = (const float*)d_in[3];
    const float* bq   = (const float*)d_in[4];
    const float* Wk   = (const float*)d_in[5];
    const float* bk   = (const float*)d_in[6];
    const float* Wv   = (const float*)d_in[7];
    const float* bv   = (const float*)d_in[8];
    const float* alp  = (const float*)d_in[9];

    char* ws = (char*)d_ws;
    const size_t XB_OFF = 0;                                  // 16,777,216 B
    const size_t WT_OFF = XB_OFF + (size_t)MROWS * HID * 2;   // + 6,291,456 B
    const size_t Q_OFF  = WT_OFF + (size_t)3 * HID * HID * 2;
    const size_t K_OFF  = Q_OFF + (size_t)MROWS * HID * 2;
    const size_t V_OFF  = K_OFF + (size_t)MROWS * HID * 2;
    const size_t B_OFF  = V_OFF + (size_t)MROWS * HID * 2;    // biasT: 33,554,432 B

    _Float16* xb   = (_Float16*)(ws + XB_OFF);
    _Float16* wt   = (_Float16*)(ws + WT_OFF);
    _Float16* Qb   = (_Float16*)(ws + Q_OFF);
    _Float16* Kb   = (_Float16*)(ws + K_OFF);
    _Float16* Vtb  = (_Float16*)(ws + V_OFF);
    _Float16* bias = (_Float16*)(ws + B_OFF);

    cvt_x<<<MROWS * HID / (256 * 8), 256, 0, stream>>>(x, xb);
    dim3 tb(32, 8);
    transw<<<dim3(32, 32), tb, 0, stream>>>(Wq, wt);
    transw<<<dim3(32, 32), tb, 0, stream>>>(Wk, wt + HID * HID);
    transw<<<dim3(32, 32), tb, 0, stream>>>(Wv, wt + 2 * HID * HID);
    mkbias<<<dim3(SEQ / 256, SEQ / 16, BATCH), 256, 0, stream>>>(tiv, msk, alp, bias);
    gemm_qkv<<<dim3(HID / 128, MROWS / 128, 3), 256, 0, stream>>>(
        xb, wt, bq, bk, bv, Qb, Kb, Vtb);
    attn<<<dim3(SEQ / 128, BATCH * HEADS), 256, 0, stream>>>(Qb, Kb, Vtb, bias,
                                                             (float*)d_out);
}

// Round 3
// 393.019 us; speedup vs baseline: 1.7054x; 1.1096x over previous
//
#include <hip/hip_runtime.h>
#include <hip/hip_bf16.h>
#include <hip/hip_fp16.h>

// Problem constants
#define BATCH 4
#define SEQ   2048
#define HID   1024
#define HEADS 16
#define HDIM  64
#define MROWS (BATCH * SEQ)   // 8192
#define LOG2E 1.4426950408889634f
#define SCL   (LOG2E / 8.0f)  // log2e / sqrt(HDIM)

typedef _Float16 v8h __attribute__((ext_vector_type(8)));
typedef _Float16 v4h __attribute__((ext_vector_type(4)));
typedef _Float16 v2h __attribute__((ext_vector_type(2)));
typedef float    v4f __attribute__((ext_vector_type(4)));
typedef int      v4i __attribute__((ext_vector_type(4)));

#define MFMA16(a, b, c) __builtin_amdgcn_mfma_f32_16x16x32_f16((a), (b), (c), 0, 0, 0)

#if __has_builtin(__builtin_amdgcn_fdot2)
#define HAVE_FDOT2 1
#else
#define HAVE_FDOT2 0
#endif

__device__ inline int pk2(float a, float b) {
    return __builtin_bit_cast(int, __builtin_amdgcn_cvt_pkrtz(a, b));
}

// async global->LDS, 16B per lane; dest = wave-uniform base + lane*16
__device__ __forceinline__ void async16(const void* g, void* l) {
    __builtin_amdgcn_global_load_lds(
        (const __attribute__((address_space(1))) unsigned int*)g,
        (__attribute__((address_space(3))) unsigned int*)l, 16, 0, 0);
}

// swizzled LDS element offset for a 64-elem (128B) row: 16B chunk ^= row&7
#define SWZ(row, chunk) (((row) * 64) + ((((chunk) ^ ((row) & 7))) * 8))

// ---------------- prep: x f32 -> f16 ----------------
__global__ __launch_bounds__(256) void cvt_x(const float* __restrict__ x,
                                             _Float16* __restrict__ xb) {
    int i = blockIdx.x * 256 + threadIdx.x;     // one thread = 8 elems
    const float4* xp = (const float4*)x;
    float4 a = xp[2 * i];
    float4 b = xp[2 * i + 1];
    v4i o;
    o[0] = pk2(a.x, a.y); o[1] = pk2(a.z, a.w);
    o[2] = pk2(b.x, b.y); o[3] = pk2(b.z, b.w);
    ((v4i*)xb)[i] = o;
}

// ---------------- prep: W [K][N] f32 -> Wt [N][K] f16 ----------------
__global__ __launch_bounds__(256) void transw(const float* __restrict__ W,
                                              _Float16* __restrict__ Wt) {
    __shared__ float t[32][33];
    int bx = blockIdx.x * 32, by = blockIdx.y * 32;
    int tx = threadIdx.x, ty = threadIdx.y;     // (32, 8)
#pragma unroll
    for (int i = 0; i < 4; i++)
        t[ty + i * 8][tx] = W[(size_t)(by + ty + i * 8) * HID + bx + tx];
    __syncthreads();
#pragma unroll
    for (int i = 0; i < 4; i++)
        Wt[(size_t)(bx + ty + i * 8) * HID + by + tx] = (_Float16)t[tx][ty + i * 8];
}

// ---------------- prep: permuted bias (MFMA S^T fragment order, f16) ----
// biasT[b][K16][Q16][lane][r] = mask ? -|a|*log2e*t : -57344
// where k = K16*16 + (lane>>4)*4 + r, q = Q16*16 + (lane&15)
__global__ __launch_bounds__(256) void mkbias(const float* __restrict__ tiv,
                                              const int* __restrict__ msk,
                                              const float* __restrict__ alphap,
                                              _Float16* __restrict__ biasT) {
    __shared__ _Float16 L[16 * 264];
    const int b = blockIdx.z, Q16 = blockIdx.y, kc0 = blockIdx.x * 256;
    const int tid = threadIdx.x;
    const float ca = -fabsf(alphap[0]) * LOG2E;
    const int prow = tid >> 6;          // 0..3
    const int pcol = (tid & 63) * 4;    // 0..252
#pragma unroll
    for (int pi = 0; pi < 4; pi++) {
        int r = pi * 4 + prow;
        size_t g = ((size_t)b * SEQ + Q16 * 16 + r) * SEQ + kc0 + pcol;
        float4 tv = *(const float4*)(tiv + g);
        int4   mv = *(const int4*)(msk + g);
        float f0 = mv.x ? ca * tv.x : -57344.0f;
        float f1 = mv.y ? ca * tv.y : -57344.0f;
        float f2 = mv.z ? ca * tv.z : -57344.0f;
        float f3 = mv.w ? ca * tv.w : -57344.0f;
        int2 o; o.x = pk2(f0, f1); o.y = pk2(f2, f3);
        *(int2*)&L[r * 264 + pcol] = o;
    }
    __syncthreads();
    const int lane = tid & 63, tq = tid >> 6;
#pragma unroll
    for (int it = 0; it < 4; it++) {
        int K16i = it * 4 + tq;
        int kl = K16i * 16 + (lane >> 4) * 4;
        int qr = lane & 15;
        int2 v = *(const int2*)&L[qr * 264 + kl];
        size_t o = ((((size_t)b * 128 + (kc0 >> 4) + K16i) * 128 + Q16) * 64 + lane) * 4;
        *(int2*)&biasT[o] = v;
    }
}

// ---------------- QKV projection GEMM (f16, async swizzled staging) -----
__global__ __launch_bounds__(256) void gemm_qkv(
    const _Float16* __restrict__ xb, const _Float16* __restrict__ wt,
    const float* __restrict__ bq, const float* __restrict__ bk,
    const float* __restrict__ bv,
    _Float16* __restrict__ Qb, _Float16* __restrict__ Kb, _Float16* __restrict__ Vtb) {
    const int mode = blockIdx.z;
    const _Float16* w = wt + (size_t)mode * HID * HID;
    __shared__ _Float16 As[128 * 64];
    __shared__ _Float16 Bs[128 * 64];
    const int tid = threadIdx.x;
    const int wv = tid >> 6, lane = tid & 63;
    const int quad = lane >> 4, l15 = lane & 15;
    const int wr = wv >> 1, wc = wv & 1;
    const int m0 = blockIdx.y * 128;
    const int n0 = blockIdx.x * 128;

    v4f acc[4][4];
#pragma unroll
    for (int i = 0; i < 4; i++)
#pragma unroll
        for (int j = 0; j < 4; j++) acc[i][j] = (v4f){0.f, 0.f, 0.f, 0.f};

    const int srow = lane >> 3;         // 0..7 within 8-row chunk
    const int schk = lane & 7;          // 16B chunk within row
    const _Float16* Ag = xb + (size_t)m0 * HID;
    const _Float16* Bg = w + (size_t)n0 * HID;

    for (int k0 = 0; k0 < HID; k0 += 64) {
        __syncthreads();
#pragma unroll
        for (int i = 0; i < 4; i++) {
            int ra = wv * 32 + i * 8 + srow;            // 0..127
            int ca = schk ^ (ra & 7);
            async16(Ag + (size_t)ra * HID + k0 + ca * 8, &As[(wv * 32 + i * 8) * 64]);
            async16(Bg + (size_t)ra * HID + k0 + ca * 8, &Bs[(wv * 32 + i * 8) * 64]);
        }
        __syncthreads();
#pragma unroll
        for (int kc = 0; kc < 2; kc++) {
            v8h af[4], bf[4];
#pragma unroll
            for (int t = 0; t < 4; t++) {
                af[t] = *(const v8h*)&As[SWZ(wr * 64 + t * 16 + l15, kc * 4 + quad)];
                bf[t] = *(const v8h*)&Bs[SWZ(wc * 64 + t * 16 + l15, kc * 4 + quad)];
            }
#pragma unroll
            for (int tm = 0; tm < 4; tm++)
#pragma unroll
                for (int tn = 0; tn < 4; tn++)
                    acc[tm][tn] = MFMA16(af[tm], bf[tn], acc[tm][tn]);
        }
    }

    const float* pb = (mode == 0) ? bq : (mode == 1 ? bk : bv);
    const float oscl = (mode == 0) ? SCL : 1.0f;   // fold log2e/8 into Q
#pragma unroll
    for (int tm = 0; tm < 4; tm++) {
#pragma unroll
        for (int tn = 0; tn < 4; tn++) {
            int n = n0 + wc * 64 + tn * 16 + l15;
            float bval = pb[n];
            int h = n >> 6, d = n & 63;
#pragma unroll
            for (int r = 0; r < 4; r++) {
                int m = m0 + wr * 64 + tm * 16 + quad * 4 + r;
                int b = m >> 11, s = m & 2047;
                _Float16 hv = (_Float16)((acc[tm][tn][r] + bval) * oscl);
                if (mode == 2) {
                    Vtb[(((size_t)(b * HEADS + h) * HDIM + d) * SEQ) + s] = hv;
                } else {
                    _Float16* dst = (mode == 0) ? Qb : Kb;
                    dst[((size_t)(b * HEADS + h) * SEQ + s) * HDIM + d] = hv;
                }
            }
        }
    }
}

// ---------------- flash attention (S^T, bias-in-accumulator) ------------
// grid (16 q-tiles, 64 b*h); block 256 (4 waves); wave owns 32 q-rows.
__global__ __launch_bounds__(256, 4) void attn(
    const _Float16* __restrict__ Qb, const _Float16* __restrict__ Kb,
    const _Float16* __restrict__ Vtb, const _Float16* __restrict__ biasT,
    float* __restrict__ out) {
    const int bh = blockIdx.y;
    const int b = bh >> 4, h = bh & 15;
    const int qt = blockIdx.x;
    const int tid = threadIdx.x;
    const int wv = tid >> 6, lane = tid & 63;
    const int quad = lane >> 4, l15 = lane & 15;

    __shared__ _Float16 Ks[64 * 64];      // [key][d], swizzled
    __shared__ _Float16 Vs[64 * 64];      // [d][key], swizzled
    __shared__ _Float16 Ps[4][32 * 64];   // per-wave P[q][key], swizzled

    const int q0 = qt * 128 + wv * 32;
    const int Q16a = q0 >> 4;             // + tm

    const _Float16* Qp = Qb + (size_t)(b * HEADS + h) * SEQ * HDIM;
    const _Float16* Kp = Kb + (size_t)(b * HEADS + h) * SEQ * HDIM;
    const _Float16* Vp = Vtb + (size_t)(b * HEADS + h) * HDIM * SEQ;
    const _Float16* Bbase = biasT + (size_t)b * 128 * 128 * 64 * 4;

    // Q fragments (B-operand: lane l15 = qrow, k = d); Q is pre-scaled by SCL
    v8h qf[2][2];
#pragma unroll
    for (int tm = 0; tm < 2; tm++)
#pragma unroll
        for (int kc = 0; kc < 2; kc++)
            qf[tm][kc] = *(const v8h*)&Qp[(size_t)(q0 + tm * 16 + l15) * HDIM + kc * 32 + quad * 8];

    v4f oacc[2][4];
#pragma unroll
    for (int i = 0; i < 2; i++)
#pragma unroll
        for (int j = 0; j < 4; j++) oacc[i][j] = (v4f){0.f, 0.f, 0.f, 0.f};
    float lsum[2] = {0.f, 0.f};
#if HAVE_FDOT2
    const v2h one2 = {(_Float16)1.0f, (_Float16)1.0f};
#endif

    const int srow = lane >> 3, schk = lane & 7;

    for (int kt = 0; kt < SEQ / 64; kt++) {
        const int key0 = kt * 64;
        // bias fragments -> accumulator init (f16 pre-multiplied by log2e)
        v4f sacc[4][2];
#pragma unroll
        for (int nt = 0; nt < 4; nt++)
#pragma unroll
            for (int tm = 0; tm < 2; tm++) {
                int2 bl = *(const int2*)&Bbase[((((size_t)(key0 >> 4) + nt) * 128 + Q16a + tm) * 64 + lane) * 4];
                v4h bv = __builtin_bit_cast(v4h, bl);
                sacc[nt][tm] = (v4f){(float)bv[0], (float)bv[1], (float)bv[2], (float)bv[3]};
            }

        __syncthreads();
        // stage K tile and V^T tile via async 16B, XOR-swizzled
#pragma unroll
        for (int i = 0; i < 2; i++) {
            int r = wv * 16 + i * 8 + srow;             // 0..63
            int c = schk ^ (r & 7);
            async16(Kp + (size_t)(key0 + r) * HDIM + c * 8, &Ks[(wv * 16 + i * 8) * 64]);
            async16(Vp + (size_t)r * SEQ + key0 + c * 8, &Vs[(wv * 16 + i * 8) * 64]);
        }
        __syncthreads();

        // S^T = K Q^T + bias : C/D row = key (quad*4+r), col = qrow (l15)
#pragma unroll
        for (int kc = 0; kc < 2; kc++) {
            v8h kfr[4];
#pragma unroll
            for (int nt = 0; nt < 4; nt++)
                kfr[nt] = *(const v8h*)&Ks[SWZ(nt * 16 + l15, kc * 4 + quad)];
#pragma unroll
            for (int nt = 0; nt < 4; nt++)
#pragma unroll
                for (int tm = 0; tm < 2; tm++)
                    sacc[nt][tm] = MFMA16(kfr[nt], qf[tm][kc], sacc[nt][tm]);
        }

        // p = exp2(sacc); per-lane partial row sums; P -> per-wave LDS
#pragma unroll
        for (int nt = 0; nt < 4; nt++)
#pragma unroll
            for (int tm = 0; tm < 2; tm++) {
                float p0 = __builtin_amdgcn_exp2f(sacc[nt][tm][0]);
                float p1 = __builtin_amdgcn_exp2f(sacc[nt][tm][1]);
                float p2 = __builtin_amdgcn_exp2f(sacc[nt][tm][2]);
                float p3 = __builtin_amdgcn_exp2f(sacc[nt][tm][3]);
                int2 pkv;
                pkv.x = pk2(p0, p1);
                pkv.y = pk2(p2, p3);
#if HAVE_FDOT2
                lsum[tm] = __builtin_amdgcn_fdot2(__builtin_bit_cast(v2h, pkv.x), one2, lsum[tm], false);
                lsum[tm] = __builtin_amdgcn_fdot2(__builtin_bit_cast(v2h, pkv.y), one2, lsum[tm], false);
#else
                lsum[tm] += (p0 + p1) + (p2 + p3);
#endif
                // write 4 consecutive keys (8B) at row q, swizzled chunk
                int q = tm * 16 + l15;
                int c16 = nt * 2 + (quad >> 1), half = quad & 1;
                *(int2*)&Ps[wv][q * 64 + ((c16 ^ (q & 7)) * 8) + half * 4] = pkv;
            }

        // O += P V  (A-frag of P from per-wave LDS; B-frag of V from V^T)
#pragma unroll
        for (int kc = 0; kc < 2; kc++) {
            v8h pf[2], vfr[4];
#pragma unroll
            for (int tm = 0; tm < 2; tm++)
                pf[tm] = *(const v8h*)&Ps[wv][SWZ(tm * 16 + l15, kc * 4 + quad)];
#pragma unroll
            for (int nt = 0; nt < 4; nt++)
                vfr[nt] = *(const v8h*)&Vs[SWZ(nt * 16 + l15, kc * 4 + quad)];
#pragma unroll
            for (int tm = 0; tm < 2; tm++)
#pragma unroll
                for (int nt = 0; nt < 4; nt++)
                    oacc[tm][nt] = MFMA16(pf[tm], vfr[nt], oacc[tm][nt]);
        }
    }

    // epilogue: reduce row sums across quads, fetch per-C/D-row inverse, store
#pragma unroll
    for (int tm = 0; tm < 2; tm++) {
        float lt = lsum[tm];
        lt += __shfl_xor(lt, 16);
        lt += __shfl_xor(lt, 32);
        float inv[4];
#pragma unroll
        for (int r = 0; r < 4; r++)
            inv[r] = 1.0f / __shfl(lt, quad * 4 + r);
#pragma unroll
        for (int nt = 0; nt < 4; nt++)
#pragma unroll
            for (int r = 0; r < 4; r++) {
                int q = q0 + tm * 16 + quad * 4 + r;
                int d = nt * 16 + l15;
                out[((size_t)b * SEQ + q) * HID + h * HDIM + d] = oacc[tm][nt][r] * inv[r];
            }
    }
}

// ---------------- launch ----------------
extern "C" void kernel_launch(void* const* d_in, const int* in_sizes, int n_in,
                              void* d_out, int out_size, void* d_ws, size_t ws_size,
                              hipStream_t stream) {
    const float* x    = (const float*)d_in[0];
    const float* tiv  = (const float*)d_in[1];
    const int*   msk  = (const int*)d_in[2];
    const float* Wq   = (const float*)d_in[3];
    const float* bq   = (const float*)d_in[4];
    const float* Wk   = (const float*)d_in[5];
    const float* bk   = (const float*)d_in[6];
    const float* Wv   = (const float*)d_in[7];
    const float* bv   = (const float*)d_in[8];
    const float* alp  = (const float*)d_in[9];

    char* ws = (char*)d_ws;
    const size_t XB_OFF = 0;                                  // 16,777,216 B
    const size_t WT_OFF = XB_OFF + (size_t)MROWS * HID * 2;   // + 6,291,456 B
    const size_t Q_OFF  = WT_OFF + (size_t)3 * HID * HID * 2;
    const size_t K_OFF  = Q_OFF + (size_t)MROWS * HID * 2;
    const size_t V_OFF  = K_OFF + (size_t)MROWS * HID * 2;
    const size_t B_OFF  = V_OFF + (size_t)MROWS * HID * 2;    // biasT: 33,554,432 B

    _Float16* xb   = (_Float16*)(ws + XB_OFF);
    _Float16* wt   = (_Float16*)(ws + WT_OFF);
    _Float16* Qb   = (_Float16*)(ws + Q_OFF);
    _Float16* Kb   = (_Float16*)(ws + K_OFF);
    _Float16* Vtb  = (_Float16*)(ws + V_OFF);
    _Float16* bias = (_Float16*)(ws + B_OFF);

    cvt_x<<<MROWS * HID / (256 * 8), 256, 0, stream>>>(x, xb);
    dim3 tb(32, 8);
    transw<<<dim3(32, 32), tb, 0, stream>>>(Wq, wt);
    transw<<<dim3(32, 32), tb, 0, stream>>>(Wk, wt + HID * HID);
    transw<<<dim3(32, 32), tb, 0, stream>>>(Wv, wt + 2 * HID * HID);
    mkbias<<<dim3(SEQ / 256, SEQ / 16, BATCH), 256, 0, stream>>>(tiv, msk, alp, bias);
    gemm_qkv<<<dim3(HID / 128, MROWS / 128, 3), 256, 0, stream>>>(
        xb, wt, bq, bk, bv, Qb, Kb, Vtb);
    attn<<<dim3(SEQ / 128, BATCH * HEADS), 256, 0, stream>>>(Qb, Kb, Vtb, bias,
                                                             (float*)d_out);
}